// Round 3
// baseline (125.856 us; speedup 1.0000x reference)
//
#include <hip/hip_runtime.h>
#include <stdint.h>

// ---------------- types ----------------
using f32x4  = __attribute__((ext_vector_type(4))) float;
using short8 = __attribute__((ext_vector_type(8))) short;
using u16x4  = __attribute__((ext_vector_type(4))) unsigned short;

#define MFMA(a, b, c) __builtin_amdgcn_mfma_f32_16x16x32_bf16((a), (b), (c), 0, 0, 0)

#define XDIM 256
#define FDIM 512
#define EPS  1e-6f

// ---- workspace layout (bytes) ----
#define QT_OFF    0u          // [512][256] bf16 = 262144
#define KT_OFF    262144u
#define VT_OFF    524288u
#define CTXT_OFF  786432u     // [32][64 e][64 d] bf16 = 262144
#define PART_OFF  1048576u    // [1024][64 d][64 e] f32 = 16 MB

// round-to-nearest-even f32 -> bf16 bits
static __device__ __forceinline__ unsigned short f2bf(float f) {
  unsigned u = __float_as_uint(f);
  unsigned r = u + 0x7FFFu + ((u >> 16) & 1u);
  return (unsigned short)(r >> 16);
}

// Stage 64 rows x 256 f32 -> bf16 LDS [64][528 B rows] (once per block).
// thread t: row = t>>2, 64-col quarter = t&3.
static __device__ __forceinline__ void stage_a_full(const float* a_rows, int tid, char* Alds) {
  const int r = tid >> 2, cq = tid & 3;
  const float* src = a_rows + (size_t)r * XDIM + cq * 64;
  char* dst = Alds + r * 528 + cq * 128;
#pragma unroll
  for (int i = 0; i < 4; ++i) {
    float4 f0 = *(const float4*)(src + i * 16);
    float4 f1 = *(const float4*)(src + i * 16 + 4);
    float4 f2 = *(const float4*)(src + i * 16 + 8);
    float4 f3 = *(const float4*)(src + i * 16 + 12);
    short8 v0, v1;
    v0[0] = (short)f2bf(f0.x); v0[1] = (short)f2bf(f0.y);
    v0[2] = (short)f2bf(f0.z); v0[3] = (short)f2bf(f0.w);
    v0[4] = (short)f2bf(f1.x); v0[5] = (short)f2bf(f1.y);
    v0[6] = (short)f2bf(f1.z); v0[7] = (short)f2bf(f1.w);
    v1[0] = (short)f2bf(f2.x); v1[1] = (short)f2bf(f2.y);
    v1[2] = (short)f2bf(f2.z); v1[3] = (short)f2bf(f2.w);
    v1[4] = (short)f2bf(f3.x); v1[5] = (short)f2bf(f3.y);
    v1[6] = (short)f2bf(f3.z); v1[7] = (short)f2bf(f3.w);
    *(short8*)(dst + i * 32)      = v0;
    *(short8*)(dst + i * 32 + 16) = v1;
  }
}

// Per-row LayerNorm over the wave's 64-col chunk (cols = nt*16 + lane&15).
static __device__ __forceinline__ void chunk_layernorm(f32x4 acc[4][4], const float* sc,
                                                       const float* bs, int lane) {
  const int lr = lane & 15;
  float scl[4], bia[4];
#pragma unroll
  for (int nt = 0; nt < 4; ++nt) { scl[nt] = sc[nt * 16 + lr]; bia[nt] = bs[nt * 16 + lr]; }
#pragma unroll
  for (int mt = 0; mt < 4; ++mt) {
#pragma unroll
    for (int j = 0; j < 4; ++j) {
      float a0 = acc[mt][0][j], a1 = acc[mt][1][j], a2 = acc[mt][2][j], a3 = acc[mt][3][j];
      float s  = a0 + a1 + a2 + a3;
      float s2 = a0 * a0 + a1 * a1 + a2 * a2 + a3 * a3;
#pragma unroll
      for (int off = 1; off < 16; off <<= 1) {
        s  += __shfl_xor(s, off, 16);
        s2 += __shfl_xor(s2, off, 16);
      }
      const float mu  = s * (1.0f / 64.0f);
      const float var = s2 * (1.0f / 64.0f) - mu * mu;
      const float rs  = rsqrtf(var + EPS);
#pragma unroll
      for (int nt = 0; nt < 4; ++nt)
        acc[mt][nt][j] = (acc[mt][nt][j] - mu) * rs * scl[nt] + bia[nt];
    }
  }
}

// ---------------- kernel 1: weight transpose/cast prep ----------------
__global__ void prep_weights_kernel(const float* __restrict__ Q, const float* __restrict__ K,
                                    const float* __restrict__ V, const float* __restrict__ ls,
                                    unsigned short* __restrict__ Qt, unsigned short* __restrict__ Kt,
                                    unsigned short* __restrict__ Vt) {
  const int flat = blockIdx.x * 256 + threadIdx.x;
  const int mat = flat >> 17;
  const int rem = flat & 131071;
  const int f = rem & 511;
  const int k = rem >> 9;
  if (mat == 0)      Qt[f * 256 + k] = f2bf(Q[k * 512 + f]);
  else if (mat == 1) Kt[f * 256 + k] = f2bf(K[k * 512 + f]);
  else               Vt[f * 256 + k] = f2bf(V[k * 512 + f] * expf(ls[f]));
}

// ---------------- kernel 2: kv projections + LN + partial ctx ----------------
// grid 1024: rb = bid>>1 (64-row tile), nb = bid&1 (256-feature half).
// Wave w covers feature chunk nb*4+w (64 cols), all 64 rows.
// Main GEMM is barrier-free: A from LDS (staged once), B streamed global->VGPR.
__launch_bounds__(256, 2)
__global__ void kv_ctx_kernel(const float* __restrict__ kv,
                              const unsigned short* __restrict__ Kt,
                              const unsigned short* __restrict__ Vt,
                              const float* __restrict__ lnk_s, const float* __restrict__ lnk_b,
                              const float* __restrict__ lnv_s, const float* __restrict__ lnv_b,
                              float* __restrict__ partials) {
  __shared__ __align__(16) char smem[33792];   // phase1: A [64][528]; phase2: knT/vnT

  const int tid = threadIdx.x, lane = tid & 63, w = tid >> 6;
  const int bid = blockIdx.x, rb = bid >> 1, nb = bid & 1;
  const int row0 = rb * 64;
  const int lr = lane & 15, lk = lane >> 4;
  const int koff = lk * 16;

  stage_a_full(kv + (size_t)row0 * XDIM, tid, smem);

  const f32x4 z4 = {0.f, 0.f, 0.f, 0.f};
  f32x4 acck[4][4], accv[4][4];
#pragma unroll
  for (int i = 0; i < 4; ++i)
#pragma unroll
    for (int j = 0; j < 4; ++j) { acck[i][j] = z4; accv[i][j] = z4; }

  const char* kbase = (const char*)Kt + (size_t)(nb * 256 + w * 64) * 512;
  const char* vbase = (const char*)Vt + (size_t)(nb * 256 + w * 64) * 512;

  __syncthreads();

  // ---- barrier-free GEMM over k=256 (4 x BK=64) ----
#pragma unroll
  for (int ks = 0; ks < 4; ++ks) {
    short8 a0[4], a1[4];
#pragma unroll
    for (int mt = 0; mt < 4; ++mt) {
      const char* ar = smem + (mt * 16 + lr) * 528 + ks * 128;
      a0[mt] = *(const short8*)(ar + koff);
      a1[mt] = *(const short8*)(ar + 64 + koff);
    }
    {
      short8 b0[4], b1[4];
#pragma unroll
      for (int nt = 0; nt < 4; ++nt) {
        const char* kr = kbase + (size_t)(nt * 16 + lr) * 512 + ks * 128 + koff;
        b0[nt] = *(const short8*)(kr);
        b1[nt] = *(const short8*)(kr + 64);
      }
#pragma unroll
      for (int mt = 0; mt < 4; ++mt)
#pragma unroll
        for (int nt = 0; nt < 4; ++nt) {
          acck[mt][nt] = MFMA(a0[mt], b0[nt], acck[mt][nt]);
          acck[mt][nt] = MFMA(a1[mt], b1[nt], acck[mt][nt]);
        }
    }
    {
      short8 b0[4], b1[4];
#pragma unroll
      for (int nt = 0; nt < 4; ++nt) {
        const char* vr = vbase + (size_t)(nt * 16 + lr) * 512 + ks * 128 + koff;
        b0[nt] = *(const short8*)(vr);
        b1[nt] = *(const short8*)(vr + 64);
      }
#pragma unroll
      for (int mt = 0; mt < 4; ++mt)
#pragma unroll
        for (int nt = 0; nt < 4; ++nt) {
          accv[mt][nt] = MFMA(a0[mt], b0[nt], accv[mt][nt]);
          accv[mt][nt] = MFMA(a1[mt], b1[nt], accv[mt][nt]);
        }
    }
  }

  chunk_layernorm(acck, lnk_s, lnk_b, lane);
  chunk_layernorm(accv, lnv_s, lnv_b, lane);

  // ---- ctx phase: ctx[d][e] += sum_t knT[d][t]*vn[t][e], t = (chunk-pair)*64 + row ----
  char* knT = smem;            // [64 d][256 B], xor-swizzled
  char* vnT = smem + 16384;
  f32x4 cacc[4];
#pragma unroll
  for (int i = 0; i < 4; ++i) cacc[i] = z4;
  const int drow = w * 16 + lr;

#pragma unroll
  for (int half = 0; half < 2; ++half) {
    __syncthreads();           // half0: A reads done; half1: half0 ctx reads done
    if ((w >> 1) == half) {    // waves holding chunks {2*half, 2*half+1} write this t-half
      const int tb2 = (w & 1) * 128;
#pragma unroll
      for (int mt = 0; mt < 4; ++mt) {
        const int tb = tb2 + mt * 32 + lk * 8;
#pragma unroll
        for (int nt = 0; nt < 4; ++nt) {
          const int d = nt * 16 + lr;
          u16x4 pk, pv;
#pragma unroll
          for (int j = 0; j < 4; ++j) {
            pk[j] = f2bf(acck[mt][nt][j]);
            pv[j] = f2bf(accv[mt][nt][j]);
          }
          const int boff = d * 256 + (tb ^ ((d & 7) << 4));
          *(u16x4*)(knT + boff) = pk;
          *(u16x4*)(vnT + boff) = pv;
        }
      }
    }
    __syncthreads();
#pragma unroll
    for (int s = 0; s < 4; ++s) {
      const short8 a = *(const short8*)(knT + drow * 256 + ((s * 64 + koff) ^ ((drow & 7) << 4)));
#pragma unroll
      for (int nt = 0; nt < 4; ++nt) {
        const int e = nt * 16 + lr;
        const short8 b = *(const short8*)(vnT + e * 256 + ((s * 64 + koff) ^ ((e & 7) << 4)));
        cacc[nt] = MFMA(a, b, cacc[nt]);
      }
    }
  }

  float* pout = partials + (size_t)bid * 4096;
#pragma unroll
  for (int nt = 0; nt < 4; ++nt)
#pragma unroll
    for (int j = 0; j < 4; ++j)
      pout[(w * 16 + lk * 4 + j) * 64 + nt * 16 + lr] = cacc[nt][j];
}

// ---------------- kernel 3: reduce partials -> ctxT (bf16, /8192, transposed) ----------------
__global__ void reduce_ctx_kernel(const float* __restrict__ partials,
                                  unsigned short* __restrict__ ctxTg) {
  const int bid = blockIdx.x, t = threadIdx.x;
  const int gg = bid >> 3, sl = bid & 7;
  const float* base = partials + (size_t)gg * 32 * 4096;
#pragma unroll
  for (int rep = 0; rep < 2; ++rep) {
    const int idx = sl * 512 + rep * 256 + t;  // idx = d*64 + e
    float acc = 0.f;
#pragma unroll 8
    for (int p = 0; p < 32; ++p) acc += base[(size_t)p * 4096 + idx];
    const int d = idx >> 6, e = idx & 63;
    ctxTg[(size_t)gg * 4096 + e * 64 + d] = f2bf(acc * (1.0f / 8192.0f));
  }
}

// ---------------- kernel 4: q projection + LN + out = qn @ ctx ----------------
__launch_bounds__(256, 2)
__global__ void q_out_kernel(const float* __restrict__ x, const unsigned short* __restrict__ Qt,
                             const unsigned short* __restrict__ ctxTg,
                             const float* __restrict__ lnq_s, const float* __restrict__ lnq_b,
                             float* __restrict__ out) {
  __shared__ __align__(16) char smem[43008];  // [0,33792): A / A2;  [33792,43008): ctxT [64][144]

  const int tid = threadIdx.x, lane = tid & 63, w = tid >> 6;
  const int bid = blockIdx.x, rb = bid >> 1, nb = bid & 1;
  const int row0 = rb * 64;
  const int g = row0 >> 10;
  const int lr = lane & 15, lk = lane >> 4;
  const int koff = lk * 16;
  char* ctxT = smem + 33792;

  stage_a_full(x + (size_t)row0 * XDIM, tid, smem);

  // stage ctxT [64 e][144 B] (padded) for this group — 32 B per thread
  {
    const unsigned short* src = ctxTg + (size_t)g * 4096 + (tid >> 2) * 64 + (tid & 3) * 16;
    char* dst = ctxT + (tid >> 2) * 144 + (tid & 3) * 32;
    *(short8*)dst        = *(const short8*)(src);
    *(short8*)(dst + 16) = *(const short8*)(src + 8);
  }

  const f32x4 z4 = {0.f, 0.f, 0.f, 0.f};
  f32x4 acc[4][4];
#pragma unroll
  for (int i = 0; i < 4; ++i)
#pragma unroll
    for (int j = 0; j < 4; ++j) acc[i][j] = z4;

  const char* qbase = (const char*)Qt + (size_t)(nb * 256 + w * 64) * 512;

  __syncthreads();

  // ---- barrier-free GEMM over k=256 ----
#pragma unroll
  for (int ks = 0; ks < 4; ++ks) {
    short8 a0[4], a1[4], b0[4], b1[4];
#pragma unroll
    for (int mt = 0; mt < 4; ++mt) {
      const char* ar = smem + (mt * 16 + lr) * 528 + ks * 128;
      a0[mt] = *(const short8*)(ar + koff);
      a1[mt] = *(const short8*)(ar + 64 + koff);
    }
#pragma unroll
    for (int nt = 0; nt < 4; ++nt) {
      const char* qr = qbase + (size_t)(nt * 16 + lr) * 512 + ks * 128 + koff;
      b0[nt] = *(const short8*)(qr);
      b1[nt] = *(const short8*)(qr + 64);
    }
#pragma unroll
    for (int mt = 0; mt < 4; ++mt)
#pragma unroll
      for (int nt = 0; nt < 4; ++nt) {
        acc[mt][nt] = MFMA(a0[mt], b0[nt], acc[mt][nt]);
        acc[mt][nt] = MFMA(a1[mt], b1[nt], acc[mt][nt]);
      }
  }

  chunk_layernorm(acc, lnq_s, lnq_b, lane);

  __syncthreads();   // all waves done reading A region

  // write qn into per-wave A2 [64 m][128 B], xor-swizzled
  char* A2 = smem + w * 8192;
#pragma unroll
  for (int mt = 0; mt < 4; ++mt)
#pragma unroll
    for (int j = 0; j < 4; ++j) {
      const int m = mt * 16 + lk * 4 + j;
      const int sw = (m & 7) << 4;
#pragma unroll
      for (int nt = 0; nt < 4; ++nt) {
        const int d = nt * 16 + lr;
        *(unsigned short*)(A2 + m * 128 + ((d * 2) ^ sw)) = f2bf(acc[mt][nt][j]);
      }
    }
  __syncthreads();

  // out MFMA: out[m][e] = sum_d qn[m][d] * ctx[d][e]
  f32x4 o[4][4];
#pragma unroll
  for (int i = 0; i < 4; ++i)
#pragma unroll
    for (int j = 0; j < 4; ++j) o[i][j] = z4;

#pragma unroll
  for (int s = 0; s < 2; ++s) {
    short8 a[4], b[4];
#pragma unroll
    for (int mt = 0; mt < 4; ++mt) {
      const int m = mt * 16 + lr;
      a[mt] = *(const short8*)(A2 + m * 128 + ((s * 64 + koff) ^ ((m & 7) << 4)));
    }
#pragma unroll
    for (int nt = 0; nt < 4; ++nt)
      b[nt] = *(const short8*)(ctxT + (nt * 16 + lr) * 144 + s * 64 + koff);
#pragma unroll
    for (int mt = 0; mt < 4; ++mt)
#pragma unroll
      for (int nt = 0; nt < 4; ++nt)
        o[mt][nt] = MFMA(a[mt], b[nt], o[mt][nt]);
  }

  // store: row = row0 + n, col = nb*256 + w*64 + e (coalesced over lr)
#pragma unroll
  for (int mt = 0; mt < 4; ++mt)
#pragma unroll
    for (int nt = 0; nt < 4; ++nt)
#pragma unroll
      for (int j = 0; j < 4; ++j) {
        const int n = mt * 16 + lk * 4 + j;
        out[(size_t)(row0 + n) * FDIM + nb * 256 + w * 64 + nt * 16 + lr] = o[mt][nt][j];
      }
}

// ---------------- launch ----------------
extern "C" void kernel_launch(void* const* d_in, const int* in_sizes, int n_in,
                              void* d_out, int out_size, void* d_ws, size_t ws_size,
                              hipStream_t stream) {
  (void)in_sizes; (void)n_in; (void)out_size; (void)ws_size;
  const float* x     = (const float*)d_in[0];
  const float* kv    = (const float*)d_in[1];
  const float* Q     = (const float*)d_in[2];
  const float* K     = (const float*)d_in[3];
  const float* V     = (const float*)d_in[4];
  const float* ls    = (const float*)d_in[5];
  const float* lnq_s = (const float*)d_in[6];
  const float* lnq_b = (const float*)d_in[7];
  const float* lnk_s = (const float*)d_in[8];
  const float* lnk_b = (const float*)d_in[9];
  const float* lnv_s = (const float*)d_in[10];
  const float* lnv_b = (const float*)d_in[11];
  float* out = (float*)d_out;

  char* ws = (char*)d_ws;
  unsigned short* Qt   = (unsigned short*)(ws + QT_OFF);
  unsigned short* Kt   = (unsigned short*)(ws + KT_OFF);
  unsigned short* Vt   = (unsigned short*)(ws + VT_OFF);
  unsigned short* ctxT = (unsigned short*)(ws + CTXT_OFF);
  float* partials      = (float*)(ws + PART_OFF);

  prep_weights_kernel<<<1536, 256, 0, stream>>>(Q, K, V, ls, Qt, Kt, Vt);
  kv_ctx_kernel<<<1024, 256, 0, stream>>>(kv, Kt, Vt, lnk_s, lnk_b, lnv_s, lnv_b, partials);
  reduce_ctx_kernel<<<256, 256, 0, stream>>>(partials, ctxT);
  q_out_kernel<<<1024, 256, 0, stream>>>(x, Qt, ctxT, lnq_s, lnq_b, out);
}

// Round 4
// 109.945 us; speedup vs baseline: 1.1447x; 1.1447x over previous
//
#include <hip/hip_runtime.h>
#include <stdint.h>

// ---------------- types ----------------
using f32x4  = __attribute__((ext_vector_type(4))) float;
using short8 = __attribute__((ext_vector_type(8))) short;
using u16x4  = __attribute__((ext_vector_type(4))) unsigned short;

#define MFMA(a, b, c) __builtin_amdgcn_mfma_f32_16x16x32_bf16((a), (b), (c), 0, 0, 0)

#define XDIM 256
#define FDIM 512
#define EPS  1e-6f

// ---- workspace layout (bytes) ----
#define QT_OFF    0u          // [512][256] bf16 = 262144
#define KT_OFF    262144u
#define VT_OFF    524288u
#define CTXT_OFF  786432u     // [32][64 e][64 d] bf16 = 262144
#define PART_OFF  1048576u    // [1024][64 d][64 e] f32 = 16 MB

// round-to-nearest-even f32 -> bf16 bits
static __device__ __forceinline__ unsigned short f2bf(float f) {
  unsigned u = __float_as_uint(f);
  unsigned r = u + 0x7FFFu + ((u >> 16) & 1u);
  return (unsigned short)(r >> 16);
}

// Stage 64 rows x 256 f32 -> bf16 LDS [64][528 B rows] (once per block).
static __device__ __forceinline__ void stage_a_full(const float* a_rows, int tid, char* Alds) {
  const int r = tid >> 2, cq = tid & 3;
  const float* src = a_rows + (size_t)r * XDIM + cq * 64;
  char* dst = Alds + r * 528 + cq * 128;
#pragma unroll
  for (int i = 0; i < 4; ++i) {
    float4 f0 = *(const float4*)(src + i * 16);
    float4 f1 = *(const float4*)(src + i * 16 + 4);
    float4 f2 = *(const float4*)(src + i * 16 + 8);
    float4 f3 = *(const float4*)(src + i * 16 + 12);
    short8 v0, v1;
    v0[0] = (short)f2bf(f0.x); v0[1] = (short)f2bf(f0.y);
    v0[2] = (short)f2bf(f0.z); v0[3] = (short)f2bf(f0.w);
    v0[4] = (short)f2bf(f1.x); v0[5] = (short)f2bf(f1.y);
    v0[6] = (short)f2bf(f1.z); v0[7] = (short)f2bf(f1.w);
    v1[0] = (short)f2bf(f2.x); v1[1] = (short)f2bf(f2.y);
    v1[2] = (short)f2bf(f2.z); v1[3] = (short)f2bf(f2.w);
    v1[4] = (short)f2bf(f3.x); v1[5] = (short)f2bf(f3.y);
    v1[6] = (short)f2bf(f3.z); v1[7] = (short)f2bf(f3.w);
    *(short8*)(dst + i * 32)      = v0;
    *(short8*)(dst + i * 32 + 16) = v1;
  }
}

// Load one 64-k B phase (8 x dwordx4) for this wave's 64-f chunk.
static __device__ __forceinline__ void load_bphase(const char* base, int ks, int lr, int koff,
                                                   short8 b[8]) {
#pragma unroll
  for (int nt = 0; nt < 4; ++nt) {
    const char* r = base + (size_t)(nt * 16 + lr) * 512 + ks * 128 + koff;
    b[nt * 2]     = *(const short8*)(r);
    b[nt * 2 + 1] = *(const short8*)(r + 64);
  }
}

// Per-row LayerNorm over the wave's 64-col chunk (cols = nt*16 + lane&15).
static __device__ __forceinline__ void chunk_layernorm(f32x4 acc[4][4], const float* sc,
                                                       const float* bs, int lane) {
  const int lr = lane & 15;
  float scl[4], bia[4];
#pragma unroll
  for (int nt = 0; nt < 4; ++nt) { scl[nt] = sc[nt * 16 + lr]; bia[nt] = bs[nt * 16 + lr]; }
#pragma unroll
  for (int mt = 0; mt < 4; ++mt) {
#pragma unroll
    for (int j = 0; j < 4; ++j) {
      float a0 = acc[mt][0][j], a1 = acc[mt][1][j], a2 = acc[mt][2][j], a3 = acc[mt][3][j];
      float s  = a0 + a1 + a2 + a3;
      float s2 = a0 * a0 + a1 * a1 + a2 * a2 + a3 * a3;
#pragma unroll
      for (int off = 1; off < 16; off <<= 1) {
        s  += __shfl_xor(s, off, 16);
        s2 += __shfl_xor(s2, off, 16);
      }
      const float mu  = s * (1.0f / 64.0f);
      const float var = s2 * (1.0f / 64.0f) - mu * mu;
      const float rs  = rsqrtf(var + EPS);
#pragma unroll
      for (int nt = 0; nt < 4; ++nt)
        acc[mt][nt][j] = (acc[mt][nt][j] - mu) * rs * scl[nt] + bia[nt];
    }
  }
}

// ---------------- kernel 1: weight transpose/cast prep ----------------
__global__ void prep_weights_kernel(const float* __restrict__ Q, const float* __restrict__ K,
                                    const float* __restrict__ V, const float* __restrict__ ls,
                                    unsigned short* __restrict__ Qt, unsigned short* __restrict__ Kt,
                                    unsigned short* __restrict__ Vt) {
  const int flat = blockIdx.x * 256 + threadIdx.x;
  const int mat = flat >> 17;
  const int rem = flat & 131071;
  const int f = rem & 511;
  const int k = rem >> 9;
  if (mat == 0)      Qt[f * 256 + k] = f2bf(Q[k * 512 + f]);
  else if (mat == 1) Kt[f * 256 + k] = f2bf(K[k * 512 + f]);
  else               Vt[f * 256 + k] = f2bf(V[k * 512 + f] * expf(ls[f]));
}

// ---------------- kernel 2: kv projections + LN + partial ctx ----------------
// grid 1024: rb = bid>>1 (64-row tile), nb = bid&1 (256-feature half).
// Barrier-free GEMM with explicit double-buffered B prefetch:
// loads for K(ks+1) issued after MFMA-K(ks), consumed after a full V phase.
__launch_bounds__(256, 2)
__global__ void kv_ctx_kernel(const float* __restrict__ kv,
                              const unsigned short* __restrict__ Kt,
                              const unsigned short* __restrict__ Vt,
                              const float* __restrict__ lnk_s, const float* __restrict__ lnk_b,
                              const float* __restrict__ lnv_s, const float* __restrict__ lnv_b,
                              float* __restrict__ partials) {
  __shared__ __align__(16) char smem[33792];   // phase1: A [64][528]; phase2: knT/vnT

  const int tid = threadIdx.x, lane = tid & 63, w = tid >> 6;
  const int bid = blockIdx.x, rb = bid >> 1, nb = bid & 1;
  const int row0 = rb * 64;
  const int lr = lane & 15, lk = lane >> 4;
  const int koff = lk * 16;

  stage_a_full(kv + (size_t)row0 * XDIM, tid, smem);

  const f32x4 z4 = {0.f, 0.f, 0.f, 0.f};
  f32x4 acck[4][4], accv[4][4];
#pragma unroll
  for (int i = 0; i < 4; ++i)
#pragma unroll
    for (int j = 0; j < 4; ++j) { acck[i][j] = z4; accv[i][j] = z4; }

  const char* kbase = (const char*)Kt + (size_t)(nb * 256 + w * 64) * 512;
  const char* vbase = (const char*)Vt + (size_t)(nb * 256 + w * 64) * 512;

  short8 bufK[8], bufV[8];
  load_bphase(kbase, 0, lr, koff, bufK);   // in flight while A staging completes
  load_bphase(vbase, 0, lr, koff, bufV);

  __syncthreads();

  // ---- barrier-free GEMM over k=256 (4 x BK=64), software-pipelined B ----
#pragma unroll
  for (int ks = 0; ks < 4; ++ks) {
    short8 a0[4], a1[4];
#pragma unroll
    for (int mt = 0; mt < 4; ++mt) {
      const char* ar = smem + (mt * 16 + lr) * 528 + ks * 128;
      a0[mt] = *(const short8*)(ar + koff);
      a1[mt] = *(const short8*)(ar + 64 + koff);
    }
    // K phase (consumes bufK loaded one full phase ago)
#pragma unroll
    for (int mt = 0; mt < 4; ++mt)
#pragma unroll
      for (int nt = 0; nt < 4; ++nt) {
        acck[mt][nt] = MFMA(a0[mt], bufK[nt * 2],     acck[mt][nt]);
        acck[mt][nt] = MFMA(a1[mt], bufK[nt * 2 + 1], acck[mt][nt]);
      }
    if (ks < 3) load_bphase(kbase, ks + 1, lr, koff, bufK);  // hide under V phase
    // V phase
#pragma unroll
    for (int mt = 0; mt < 4; ++mt)
#pragma unroll
      for (int nt = 0; nt < 4; ++nt) {
        accv[mt][nt] = MFMA(a0[mt], bufV[nt * 2],     accv[mt][nt]);
        accv[mt][nt] = MFMA(a1[mt], bufV[nt * 2 + 1], accv[mt][nt]);
      }
    if (ks < 3) load_bphase(vbase, ks + 1, lr, koff, bufV);  // hide under next K phase
  }

  chunk_layernorm(acck, lnk_s, lnk_b, lane);
  chunk_layernorm(accv, lnv_s, lnv_b, lane);

  // ---- ctx phase: ctx[d][e] += sum_t knT[d][t]*vn[t][e], t = (chunk-pair)*64 + row ----
  char* knT = smem;            // [64 d][256 B], xor-swizzled
  char* vnT = smem + 16384;
  f32x4 cacc[4];
#pragma unroll
  for (int i = 0; i < 4; ++i) cacc[i] = z4;
  const int drow = w * 16 + lr;

#pragma unroll
  for (int half = 0; half < 2; ++half) {
    __syncthreads();           // half0: A reads done; half1: half0 ctx reads done
    if ((w >> 1) == half) {    // waves holding chunks {2*half, 2*half+1} write this t-half
      const int tb2 = (w & 1) * 128;
#pragma unroll
      for (int mt = 0; mt < 4; ++mt) {
        const int tb = tb2 + mt * 32 + lk * 8;
#pragma unroll
        for (int nt = 0; nt < 4; ++nt) {
          const int d = nt * 16 + lr;
          u16x4 pk, pv;
#pragma unroll
          for (int j = 0; j < 4; ++j) {
            pk[j] = f2bf(acck[mt][nt][j]);
            pv[j] = f2bf(accv[mt][nt][j]);
          }
          const int boff = d * 256 + (tb ^ ((d & 7) << 4));
          *(u16x4*)(knT + boff) = pk;
          *(u16x4*)(vnT + boff) = pv;
        }
      }
    }
    __syncthreads();
#pragma unroll
    for (int s = 0; s < 4; ++s) {
      const short8 a = *(const short8*)(knT + drow * 256 + ((s * 64 + koff) ^ ((drow & 7) << 4)));
#pragma unroll
      for (int nt = 0; nt < 4; ++nt) {
        const int e = nt * 16 + lr;
        const short8 b = *(const short8*)(vnT + e * 256 + ((s * 64 + koff) ^ ((e & 7) << 4)));
        cacc[nt] = MFMA(a, b, cacc[nt]);
      }
    }
  }

  float* pout = partials + (size_t)bid * 4096;
#pragma unroll
  for (int nt = 0; nt < 4; ++nt)
#pragma unroll
    for (int j = 0; j < 4; ++j)
      pout[(w * 16 + lk * 4 + j) * 64 + nt * 16 + lr] = cacc[nt][j];
}

// ---------------- kernel 3: reduce partials -> ctxT (bf16, /8192, transposed) ----------------
__global__ void reduce_ctx_kernel(const float* __restrict__ partials,
                                  unsigned short* __restrict__ ctxTg) {
  const int bid = blockIdx.x, t = threadIdx.x;
  const int gg = bid >> 3, sl = bid & 7;
  const float* base = partials + (size_t)gg * 32 * 4096;
#pragma unroll
  for (int rep = 0; rep < 2; ++rep) {
    const int idx = sl * 512 + rep * 256 + t;  // idx = d*64 + e
    float acc = 0.f;
#pragma unroll 8
    for (int p = 0; p < 32; ++p) acc += base[(size_t)p * 4096 + idx];
    const int d = idx >> 6, e = idx & 63;
    ctxTg[(size_t)gg * 4096 + e * 64 + d] = f2bf(acc * (1.0f / 8192.0f));
  }
}

// ---------------- kernel 4: q projection + LN + out = qn @ ctx ----------------
__launch_bounds__(256, 2)
__global__ void q_out_kernel(const float* __restrict__ x, const unsigned short* __restrict__ Qt,
                             const unsigned short* __restrict__ ctxTg,
                             const float* __restrict__ lnq_s, const float* __restrict__ lnq_b,
                             float* __restrict__ out) {
  __shared__ __align__(16) char smem[43008];  // [0,33792): A / A2;  [33792,43008): ctxT [64][144]

  const int tid = threadIdx.x, lane = tid & 63, w = tid >> 6;
  const int bid = blockIdx.x, rb = bid >> 1, nb = bid & 1;
  const int row0 = rb * 64;
  const int g = row0 >> 10;
  const int lr = lane & 15, lk = lane >> 4;
  const int koff = lk * 16;
  char* ctxT = smem + 33792;

  stage_a_full(x + (size_t)row0 * XDIM, tid, smem);

  // stage ctxT [64 e][144 B] (padded) for this group — 32 B per thread
  {
    const unsigned short* src = ctxTg + (size_t)g * 4096 + (tid >> 2) * 64 + (tid & 3) * 16;
    char* dst = ctxT + (tid >> 2) * 144 + (tid & 3) * 32;
    *(short8*)dst        = *(const short8*)(src);
    *(short8*)(dst + 16) = *(const short8*)(src + 8);
  }

  const f32x4 z4 = {0.f, 0.f, 0.f, 0.f};
  f32x4 acc[4][4];
#pragma unroll
  for (int i = 0; i < 4; ++i)
#pragma unroll
    for (int j = 0; j < 4; ++j) acc[i][j] = z4;

  const char* qbase = (const char*)Qt + (size_t)(nb * 256 + w * 64) * 512;

  short8 buf0[8], buf1[8];
  load_bphase(qbase, 0, lr, koff, buf0);

  __syncthreads();

  // ---- barrier-free GEMM over k=256, alternating prefetch buffers ----
#pragma unroll
  for (int ks = 0; ks < 4; ++ks) {
    // issue next phase's loads before consuming current
    if (ks == 0) load_bphase(qbase, 1, lr, koff, buf1);
    if (ks == 1) load_bphase(qbase, 2, lr, koff, buf0);
    if (ks == 2) load_bphase(qbase, 3, lr, koff, buf1);
    short8 a0[4], a1[4];
#pragma unroll
    for (int mt = 0; mt < 4; ++mt) {
      const char* ar = smem + (mt * 16 + lr) * 528 + ks * 128;
      a0[mt] = *(const short8*)(ar + koff);
      a1[mt] = *(const short8*)(ar + 64 + koff);
    }
#pragma unroll
    for (int mt = 0; mt < 4; ++mt)
#pragma unroll
      for (int nt = 0; nt < 4; ++nt) {
        if ((ks & 1) == 0) {
          acc[mt][nt] = MFMA(a0[mt], buf0[nt * 2],     acc[mt][nt]);
          acc[mt][nt] = MFMA(a1[mt], buf0[nt * 2 + 1], acc[mt][nt]);
        } else {
          acc[mt][nt] = MFMA(a0[mt], buf1[nt * 2],     acc[mt][nt]);
          acc[mt][nt] = MFMA(a1[mt], buf1[nt * 2 + 1], acc[mt][nt]);
        }
      }
  }

  chunk_layernorm(acc, lnq_s, lnq_b, lane);

  __syncthreads();   // all waves done reading A region

  // write qn into per-wave A2 [64 m][128 B], xor-swizzled
  char* A2 = smem + w * 8192;
#pragma unroll
  for (int mt = 0; mt < 4; ++mt)
#pragma unroll
    for (int j = 0; j < 4; ++j) {
      const int m = mt * 16 + lk * 4 + j;
      const int sw = (m & 7) << 4;
#pragma unroll
      for (int nt = 0; nt < 4; ++nt) {
        const int d = nt * 16 + lr;
        *(unsigned short*)(A2 + m * 128 + ((d * 2) ^ sw)) = f2bf(acc[mt][nt][j]);
      }
    }
  __syncthreads();

  // out MFMA: out[m][e] = sum_d qn[m][d] * ctx[d][e]
  f32x4 o[4][4];
#pragma unroll
  for (int i = 0; i < 4; ++i)
#pragma unroll
    for (int j = 0; j < 4; ++j) o[i][j] = z4;

#pragma unroll
  for (int s = 0; s < 2; ++s) {
    short8 a[4], b[4];
#pragma unroll
    for (int mt = 0; mt < 4; ++mt) {
      const int m = mt * 16 + lr;
      a[mt] = *(const short8*)(A2 + m * 128 + ((s * 64 + koff) ^ ((m & 7) << 4)));
    }
#pragma unroll
    for (int nt = 0; nt < 4; ++nt)
      b[nt] = *(const short8*)(ctxT + (nt * 16 + lr) * 144 + s * 64 + koff);
#pragma unroll
    for (int mt = 0; mt < 4; ++mt)
#pragma unroll
      for (int nt = 0; nt < 4; ++nt)
        o[mt][nt] = MFMA(a[mt], b[nt], o[mt][nt]);
  }

  // store: row = row0 + n, col = nb*256 + w*64 + e (coalesced over lr)
#pragma unroll
  for (int mt = 0; mt < 4; ++mt)
#pragma unroll
    for (int nt = 0; nt < 4; ++nt)
#pragma unroll
      for (int j = 0; j < 4; ++j) {
        const int n = mt * 16 + lk * 4 + j;
        out[(size_t)(row0 + n) * FDIM + nb * 256 + w * 64 + nt * 16 + lr] = o[mt][nt][j];
      }
}

// ---------------- launch ----------------
extern "C" void kernel_launch(void* const* d_in, const int* in_sizes, int n_in,
                              void* d_out, int out_size, void* d_ws, size_t ws_size,
                              hipStream_t stream) {
  (void)in_sizes; (void)n_in; (void)out_size; (void)ws_size;
  const float* x     = (const float*)d_in[0];
  const float* kv    = (const float*)d_in[1];
  const float* Q     = (const float*)d_in[2];
  const float* K     = (const float*)d_in[3];
  const float* V     = (const float*)d_in[4];
  const float* ls    = (const float*)d_in[5];
  const float* lnq_s = (const float*)d_in[6];
  const float* lnq_b = (const float*)d_in[7];
  const float* lnk_s = (const float*)d_in[8];
  const float* lnk_b = (const float*)d_in[9];
  const float* lnv_s = (const float*)d_in[10];
  const float* lnv_b = (const float*)d_in[11];
  float* out = (float*)d_out;

  char* ws = (char*)d_ws;
  unsigned short* Qt   = (unsigned short*)(ws + QT_OFF);
  unsigned short* Kt   = (unsigned short*)(ws + KT_OFF);
  unsigned short* Vt   = (unsigned short*)(ws + VT_OFF);
  unsigned short* ctxT = (unsigned short*)(ws + CTXT_OFF);
  float* partials      = (float*)(ws + PART_OFF);

  prep_weights_kernel<<<1536, 256, 0, stream>>>(Q, K, V, ls, Qt, Kt, Vt);
  kv_ctx_kernel<<<1024, 256, 0, stream>>>(kv, Kt, Vt, lnk_s, lnk_b, lnv_s, lnv_b, partials);
  reduce_ctx_kernel<<<256, 256, 0, stream>>>(partials, ctxT);
  q_out_kernel<<<1024, 256, 0, stream>>>(x, Qt, ctxT, lnq_s, lnq_b, out);
}